// Round 9
// baseline (42.312 us; speedup 1.0000x reference)
//
#include <hip/hip_runtime.h>

// BipolarMorphological2D SMorph:
//   out[b,o,s] = exp(sm(p1,k1)) - exp(sm(p1,k2)) - exp(sm(p2,k1)) + exp(sm(p2,k2)) + bias[o]
// with sm = sum(z*e^z)/sum(e^z), z = log(max(+/-x,0.1)) + kf[p,o].
// Factorization: e^z = m * e^kf ; z*e^z = (m*lm)*e^kf + m*(kf*e^kf)
// -> fp32 pk-FMA reductions over P=288, no transcendentals in the hot loop.
//
// R9: eliminate the per-CU scalar/SMEM unit from the hot path (the theory for
// the TLP-invariant ~28us floor of R1/R3/R4/R8: all kept A on s_load; sK$ has
// one unit + few MSHRs per CU shared by 4 SIMDs). A is now PRELOADED per
// (row, c-half): 12 uniform-address VMEM b128 loads (laundered via "+v" asm
// so they can't be re-scalarized) feeding 144 pk-FMAs from registers; the
// inner loop contains ONLY coalesced B loads (vmcnt) + pk-FMAs. Grid is
// row-aligned: (8 wo-tiles x 30 ho x 4 b) = 960 blocks, 8 waves, kq-split 8.

typedef float v2f __attribute__((ext_vector_type(2)));

#define BB   4
#define CC   32
#define HH   32
#define WW   32
#define OO   64
#define HO   30
#define WO   30
#define NSP  (HO*WO)   // 900

// ---- prep: A[b,h,w,c] = (mp, mn, mp*log mp, mn*log mn)
//            Bm[ij,c,o] = (e^k1, k1*e^k1, e^k2, k2*e^k2)
__global__ __launch_bounds__(256) void smorph_prep(
    const float* __restrict__ x, const float* __restrict__ k1,
    const float* __restrict__ k2, float4* __restrict__ A, float4* __restrict__ Bm)
{
    int t = blockIdx.x * 256 + threadIdx.x;
    if (t < BB*CC*HH*WW) {
        float v = x[t];
        int b = t >> 15, c = (t >> 10) & 31, h = (t >> 5) & 31, w = t & 31;
        float mp = fmaxf(v, 0.1f), mn = fmaxf(-v, 0.1f);
        A[((b*HH + h)*WW + w)*CC + c] =
            make_float4(mp, mn, mp*logf(mp), mn*logf(mn));
    }
    if (t < 9*CC*OO) {
        float a = k1[t], bb = k2[t];
        float e1 = expf(a), e2 = expf(bb);
        Bm[t] = make_float4(e1, a*e1, e2, bb*e2);
    }
}

// Pin a pointer in VGPRs so uniform-address loads stay on the VMEM pipe
// (compiler would otherwise scalarize them back to s_load).
__device__ __forceinline__ const float4* as_vgpr(const float4* p) {
    asm("" : "+v"(p));
    return p;
}

// grid (8, 30, 4): x = wo-tile (4 positions, same row), y = ho, z = b.
__global__ __launch_bounds__(512, 4) void smorph_main(
    const float4* __restrict__ A, const float4* __restrict__ Bm,
    const float* __restrict__ bias, float* __restrict__ out)
{
    __shared__ v2f ldsr[4*16*64];   // 32 KB combine scratch (used only at end)

    const int tid = threadIdx.x;
    const int o   = tid & 63;
    const int kq  = __builtin_amdgcn_readfirstlane(tid >> 6);  // wave 0..7, c-range [4kq,4kq+4)
    const int w0  = blockIdx.x * 4;   // 0,4,...,28 (tile 7 has 2 dup positions)
    const int ho  = blockIdx.y;
    const int b   = blockIdx.z;

    int wcol[6];                      // clamped pixel columns of the 6-wide window
#pragma unroll
    for (int p = 0; p < 6; ++p) { int w = w0 + p; wcol[p] = (w > WW-1) ? (WW-1) : w; }

    v2f P1d[4] = {}, P1n[4] = {}, P2d[4] = {}, P2n[4] = {};

    const float4* Bq = Bm + kq*4*OO + o;     // lane-coalesced B base
    const float4* Af = as_vgpr(A);           // uniform A -> VMEM, never SMEM

#pragma unroll
    for (int i = 0; i < 3; ++i) {
        const int rowb = ((b*HH + ho + i)*WW)*CC + kq*4;
#pragma unroll
        for (int ch = 0; ch < 2; ++ch) {     // c-half: 2 channels each
            float4 ar[12];                   // 6 pixels x 2 c, 48 VGPRs
#pragma unroll
            for (int p = 0; p < 6; ++p)
#pragma unroll
                for (int c = 0; c < 2; ++c)
                    ar[p*2 + c] = Af[rowb + wcol[p]*CC + ch*2 + c];

#pragma unroll
            for (int j = 0; j < 3; ++j) {
                const int ij = i*3 + j;
                float4 Bv[2];
#pragma unroll
                for (int c = 0; c < 2; ++c)
                    Bv[c] = Bq[ij*(CC*OO) + (ch*2 + c)*OO];   // coalesced, L2

#pragma unroll
                for (int c = 0; c < 2; ++c) {
                    v2f be1 = {Bv[c].x, Bv[c].x}, bk1 = {Bv[c].y, Bv[c].y};
                    v2f be2 = {Bv[c].z, Bv[c].z}, bk2 = {Bv[c].w, Bv[c].w};
#pragma unroll
                    for (int t = 0; t < 4; ++t) {
                        float4 Av = ar[(t + j)*2 + c];   // registers, static idx
                        v2f a1 = {Av.x, Av.y};           // (mp, mn)
                        v2f a2 = {Av.z, Av.w};           // (mp*lmp, mn*lmn)
                        P1d[t] += a1 * be1;
                        P1n[t] += a2 * be1;
                        P1n[t] += a1 * bk1;
                        P2d[t] += a1 * be2;
                        P2n[t] += a2 * be2;
                        P2n[t] += a1 * bk2;
                    }
                }
            }
        }
    }

    // ---- combine K-split partials across 8 waves: 3-level LDS tree
    if (kq >= 4) {
        v2f* dst = ldsr + (kq - 4)*1024 + o;
#pragma unroll
        for (int t = 0; t < 4; ++t) {
            dst[(t*4+0)*64] = P1d[t];
            dst[(t*4+1)*64] = P1n[t];
            dst[(t*4+2)*64] = P2d[t];
            dst[(t*4+3)*64] = P2n[t];
        }
    }
    __syncthreads();
    if (kq < 4) {
        const v2f* srcp = ldsr + kq*1024 + o;
#pragma unroll
        for (int t = 0; t < 4; ++t) {
            P1d[t] += srcp[(t*4+0)*64];
            P1n[t] += srcp[(t*4+1)*64];
            P2d[t] += srcp[(t*4+2)*64];
            P2n[t] += srcp[(t*4+3)*64];
        }
    }
    __syncthreads();
    if (kq == 2 || kq == 3) {
        v2f* dst = ldsr + (kq - 2)*1024 + o;
#pragma unroll
        for (int t = 0; t < 4; ++t) {
            dst[(t*4+0)*64] = P1d[t];
            dst[(t*4+1)*64] = P1n[t];
            dst[(t*4+2)*64] = P2d[t];
            dst[(t*4+3)*64] = P2n[t];
        }
    }
    __syncthreads();
    if (kq < 2) {
        const v2f* srcp = ldsr + kq*1024 + o;
#pragma unroll
        for (int t = 0; t < 4; ++t) {
            P1d[t] += srcp[(t*4+0)*64];
            P1n[t] += srcp[(t*4+1)*64];
            P2d[t] += srcp[(t*4+2)*64];
            P2n[t] += srcp[(t*4+3)*64];
        }
    }
    __syncthreads();
    if (kq == 1) {
        v2f* dst = ldsr + o;
#pragma unroll
        for (int t = 0; t < 4; ++t) {
            dst[(t*4+0)*64] = P1d[t];
            dst[(t*4+1)*64] = P1n[t];
            dst[(t*4+2)*64] = P2d[t];
            dst[(t*4+3)*64] = P2n[t];
        }
    }
    __syncthreads();
    if (kq == 0) {
        const v2f* srcp = ldsr + o;
        const float bo = bias[o];
#pragma unroll
        for (int t = 0; t < 4; ++t) {
            v2f d1 = P1d[t] + srcp[(t*4+0)*64];
            v2f n1 = P1n[t] + srcp[(t*4+1)*64];
            v2f d2 = P2d[t] + srcp[(t*4+2)*64];
            v2f n2 = P2n[t] + srcp[(t*4+3)*64];
            int wo = w0 + t;
            if (wo < WO) {
                float r = expf(n1.x/d1.x) - expf(n2.x/d2.x)
                        - expf(n1.y/d1.y) + expf(n2.y/d2.y) + bo;
                out[(size_t)(b*OO + o)*NSP + ho*WO + wo] = r;
            }
        }
    }
}

extern "C" void kernel_launch(void* const* d_in, const int* in_sizes, int n_in,
                              void* d_out, int out_size, void* d_ws, size_t ws_size,
                              hipStream_t stream) {
    const float* x    = (const float*)d_in[0];
    const float* k1   = (const float*)d_in[1];
    const float* k2   = (const float*)d_in[2];
    const float* bias = (const float*)d_in[3];

    float4* A  = (float4*)d_ws;                                   // 2 MB
    float4* Bm = (float4*)((char*)d_ws + (size_t)BB*HH*WW*CC*16); // 294 KB
    float*  out = (float*)d_out;

    hipLaunchKernelGGL(smorph_prep, dim3((BB*CC*HH*WW + 255)/256), dim3(256), 0, stream,
                       x, k1, k2, A, Bm);

    hipLaunchKernelGGL(smorph_main, dim3(8, HO, BB), dim3(512), 0, stream,
                       A, Bm, bias, out);
}

// Round 10
// 36.097 us; speedup vs baseline: 1.1722x; 1.1722x over previous
//
#include <hip/hip_runtime.h>

// BipolarMorphological2D SMorph:
//   out[b,o,s] = exp(sm(p1,k1)) - exp(sm(p1,k2)) - exp(sm(p2,k1)) + exp(sm(p2,k2)) + bias[o]
// with sm = sum(z*e^z)/sum(e^z), z = log(max(+/-x,0.1)) + kf[p,o].
// Factorization: e^z = m * e^kf ; z*e^z = (m*lm)*e^kf + m*(kf*e^kf)
// -> fp32 pk-FMA reductions over P=288, no transcendentals in the hot loop.
//
// R10: A broadcast operand moved to LDS-with-register-reuse. The ~28us floor
// of R4/R8 was the per-CU scalar unit (~1000 s_load_dwordx16/CU at ~300cyc
// serial-ish); R6 failed because it read A from LDS per-FMA-group (288 full-
// cost reads/wave); R9 failed because A-preloads shared the in-order vmcnt
// counter with B. Fix: stage the block's 3x6-pixel A window (9.2KB) in LDS
// once; per (row, c-pair) read 12 BROADCAST ds_read_b128 (~16B served, cheap)
// into 48 VGPRs, reused across 3 j-phases x 4 positions (144 pk-FMAs); B is
// the only vmcnt user (coalesced L2 streams). lgkm domain = LDS only.

typedef float v2f __attribute__((ext_vector_type(2)));

#define BB   4
#define CC   32
#define HH   32
#define WW   32
#define OO   64
#define HO   30
#define WO   30
#define NSP  (HO*WO)   // 900

// ---- prep: A[b,h,w,c] = (mp, mn, mp*log mp, mn*log mn)
//            Bm[ij,c,o] = (e^k1, k1*e^k1, e^k2, k2*e^k2)
__global__ __launch_bounds__(256) void smorph_prep(
    const float* __restrict__ x, const float* __restrict__ k1,
    const float* __restrict__ k2, float4* __restrict__ A, float4* __restrict__ Bm)
{
    int t = blockIdx.x * 256 + threadIdx.x;
    if (t < BB*CC*HH*WW) {
        float v = x[t];
        int b = t >> 15, c = (t >> 10) & 31, h = (t >> 5) & 31, w = t & 31;
        float mp = fmaxf(v, 0.1f), mn = fmaxf(-v, 0.1f);
        A[((b*HH + h)*WW + w)*CC + c] =
            make_float4(mp, mn, mp*logf(mp), mn*logf(mn));
    }
    if (t < 9*CC*OO) {
        float a = k1[t], bb = k2[t];
        float e1 = expf(a), e2 = expf(bb);
        Bm[t] = make_float4(e1, a*e1, e2, bb*e2);
    }
}

// grid (8, 30, 4): x = wo-tile (4 positions, one row), y = ho, z = b. 8 waves.
__global__ __launch_bounds__(512, 4) void smorph_main(
    const float4* __restrict__ A, const float4* __restrict__ Bm,
    const float* __restrict__ bias, float* __restrict__ out)
{
    __shared__ __align__(16) char ldsbuf[32768];
    float4* ldsA = (float4*)ldsbuf;   // [pix 0..17][c 0..31] staging (9.2 KB)
    v2f*    ldsr = (v2f*)ldsbuf;      // combine scratch view (32 KB)

    const int tid = threadIdx.x;
    const int o   = tid & 63;
    const int kq  = __builtin_amdgcn_readfirstlane(tid >> 6);  // wave 0..7, c-range [4kq,4kq+4)
    const int w0  = blockIdx.x * 4;   // 0..28 (last tile: 2 masked positions)
    const int ho  = blockIdx.y;
    const int b   = blockIdx.z;

    // ---- stage A window: rows ho..ho+2, cols w0..w0+5 (clamped), all 32 c
    for (int u = tid; u < 18*CC; u += 512) {
        int c = u & 31, pix = u >> 5;          // pix = r*6 + wp
        int r = pix / 6, wp = pix - 6*r;
        int w = w0 + wp; if (w > WW-1) w = WW-1;
        ldsA[u] = A[((b*HH + ho + r)*WW + w)*CC + c];
    }
    __syncthreads();

    v2f P1d[4] = {}, P1n[4] = {}, P2d[4] = {}, P2n[4] = {};

    const float4* Bq = Bm + kq*4*OO + o;       // lane-coalesced B base (vmcnt only)

#pragma unroll
    for (int i = 0; i < 3; ++i) {
#pragma unroll
        for (int ch = 0; ch < 2; ++ch) {       // c-pair within the wave's 4-c range
            float4 ar[12];                     // 6 pixels x 2 c, broadcast ds_read_b128
#pragma unroll
            for (int p = 0; p < 6; ++p)
#pragma unroll
                for (int c = 0; c < 2; ++c)
                    ar[p*2 + c] = ldsA[(i*6 + p)*CC + kq*4 + ch*2 + c];

#pragma unroll
            for (int j = 0; j < 3; ++j) {
                const int ij = i*3 + j;
                float4 Bv[2];
#pragma unroll
                for (int c = 0; c < 2; ++c)
                    Bv[c] = Bq[ij*(CC*OO) + (ch*2 + c)*OO];   // coalesced, L2-hot

#pragma unroll
                for (int c = 0; c < 2; ++c) {
                    v2f be1 = {Bv[c].x, Bv[c].x}, bk1 = {Bv[c].y, Bv[c].y};
                    v2f be2 = {Bv[c].z, Bv[c].z}, bk2 = {Bv[c].w, Bv[c].w};
#pragma unroll
                    for (int t = 0; t < 4; ++t) {
                        float4 Av = ar[(t + j)*2 + c];   // registers, static idx
                        v2f a1 = {Av.x, Av.y};           // (mp, mn)
                        v2f a2 = {Av.z, Av.w};           // (mp*lmp, mn*lmn)
                        P1d[t] += a1 * be1;
                        P1n[t] += a2 * be1;
                        P1n[t] += a1 * bk1;
                        P2d[t] += a1 * be2;
                        P2n[t] += a2 * be2;
                        P2n[t] += a1 * bk2;
                    }
                }
            }
        }
    }

    __syncthreads();   // staging reads done; LDS reused for combine

    // ---- combine K-split partials across 8 waves: 3-level LDS tree
    if (kq >= 4) {
        v2f* dst = ldsr + (kq - 4)*1024 + o;
#pragma unroll
        for (int t = 0; t < 4; ++t) {
            dst[(t*4+0)*64] = P1d[t];
            dst[(t*4+1)*64] = P1n[t];
            dst[(t*4+2)*64] = P2d[t];
            dst[(t*4+3)*64] = P2n[t];
        }
    }
    __syncthreads();
    if (kq < 4) {
        const v2f* srcp = ldsr + kq*1024 + o;
#pragma unroll
        for (int t = 0; t < 4; ++t) {
            P1d[t] += srcp[(t*4+0)*64];
            P1n[t] += srcp[(t*4+1)*64];
            P2d[t] += srcp[(t*4+2)*64];
            P2n[t] += srcp[(t*4+3)*64];
        }
    }
    __syncthreads();
    if (kq == 2 || kq == 3) {
        v2f* dst = ldsr + (kq - 2)*1024 + o;
#pragma unroll
        for (int t = 0; t < 4; ++t) {
            dst[(t*4+0)*64] = P1d[t];
            dst[(t*4+1)*64] = P1n[t];
            dst[(t*4+2)*64] = P2d[t];
            dst[(t*4+3)*64] = P2n[t];
        }
    }
    __syncthreads();
    if (kq < 2) {
        const v2f* srcp = ldsr + kq*1024 + o;
#pragma unroll
        for (int t = 0; t < 4; ++t) {
            P1d[t] += srcp[(t*4+0)*64];
            P1n[t] += srcp[(t*4+1)*64];
            P2d[t] += srcp[(t*4+2)*64];
            P2n[t] += srcp[(t*4+3)*64];
        }
    }
    __syncthreads();
    if (kq == 1) {
        v2f* dst = ldsr + o;
#pragma unroll
        for (int t = 0; t < 4; ++t) {
            dst[(t*4+0)*64] = P1d[t];
            dst[(t*4+1)*64] = P1n[t];
            dst[(t*4+2)*64] = P2d[t];
            dst[(t*4+3)*64] = P2n[t];
        }
    }
    __syncthreads();
    if (kq == 0) {
        const v2f* srcp = ldsr + o;
        const float bo = bias[o];
#pragma unroll
        for (int t = 0; t < 4; ++t) {
            v2f d1 = P1d[t] + srcp[(t*4+0)*64];
            v2f n1 = P1n[t] + srcp[(t*4+1)*64];
            v2f d2 = P2d[t] + srcp[(t*4+2)*64];
            v2f n2 = P2n[t] + srcp[(t*4+3)*64];
            int wo = w0 + t;
            if (wo < WO) {
                float r = expf(n1.x/d1.x) - expf(n2.x/d2.x)
                        - expf(n1.y/d1.y) + expf(n2.y/d2.y) + bo;
                out[(size_t)(b*OO + o)*NSP + ho*WO + wo] = r;
            }
        }
    }
}

extern "C" void kernel_launch(void* const* d_in, const int* in_sizes, int n_in,
                              void* d_out, int out_size, void* d_ws, size_t ws_size,
                              hipStream_t stream) {
    const float* x    = (const float*)d_in[0];
    const float* k1   = (const float*)d_in[1];
    const float* k2   = (const float*)d_in[2];
    const float* bias = (const float*)d_in[3];

    float4* A  = (float4*)d_ws;                                   // 2 MB
    float4* Bm = (float4*)((char*)d_ws + (size_t)BB*HH*WW*CC*16); // 294 KB
    float*  out = (float*)d_out;

    hipLaunchKernelGGL(smorph_prep, dim3((BB*CC*HH*WW + 255)/256), dim3(256), 0, stream,
                       x, k1, k2, A, Bm);

    hipLaunchKernelGGL(smorph_main, dim3(8, HO, BB), dim3(512), 0, stream,
                       A, Bm, bias, out);
}